// Round 1
// baseline (262.251 us; speedup 1.0000x reference)
//
#include <hip/hip_runtime.h>

// DistanceCentroidLoss: N=262144 points (D=128) vs K=64 centroids, fp32.
// loss = ( sum_k mean_{i in k} d_own^2  +  sum_k mean_{i in k} rowrep_i ) / K
// rowrep_i = (sum_j (5-d_ij)^2 - (5-d_own)^2) / (K-1)
// relu((5-d)^2) is a no-op (arg >= 0), so sum_j (5-d)^2 = 25K - 10*sum_d + sum_d2.

constexpr int N = 262144;
constexpr int D = 128;
constexpr int K = 64;
constexpr float MARGIN = 5.0f;

__global__ __launch_bounds__(256) void dcl_main(
    const float* __restrict__ emb,
    const int*   __restrict__ labels,
    const float* __restrict__ cent,
    float* __restrict__ g_attr,
    float* __restrict__ g_rep,
    int*   __restrict__ g_cnt)
{
    __shared__ float sC[K * D];   // 32 KB centroids
    __shared__ float sc2[K];
    __shared__ float s_attr[K];
    __shared__ float s_rep[K];
    __shared__ int   s_cnt[K];

    const int tid = threadIdx.x;

    // stage centroids into LDS (vectorized, coalesced)
    const float4* c4 = (const float4*)cent;
    float4* s4 = (float4*)sC;
    #pragma unroll
    for (int idx = tid; idx < K * D / 4; idx += 256) s4[idx] = c4[idx];
    if (tid < K) { s_attr[tid] = 0.f; s_rep[tid] = 0.f; s_cnt[tid] = 0; }
    __syncthreads();

    if (tid < K) {
        float s = 0.f;
        #pragma unroll 8
        for (int d = 0; d < D; ++d) { float v = sC[tid * D + d]; s = fmaf(v, v, s); }
        sc2[tid] = s;
    }
    __syncthreads();

    const int i = blockIdx.x * 256 + tid;   // grid sized so i < N always

    float acc[K];
    #pragma unroll
    for (int k = 0; k < K; ++k) acc[k] = 0.f;

    float x2 = 0.f;
    const float4* xv = (const float4*)(emb + (size_t)i * D);

    #pragma unroll 4
    for (int dc = 0; dc < D / 4; ++dc) {
        const float4 v = xv[dc];
        x2 = fmaf(v.x, v.x, x2);
        x2 = fmaf(v.y, v.y, x2);
        x2 = fmaf(v.z, v.z, x2);
        x2 = fmaf(v.w, v.w, x2);
        #pragma unroll
        for (int k = 0; k < K; ++k) {
            // wave-uniform address -> LDS broadcast, conflict-free
            const float4 c = *(const float4*)&sC[k * D + dc * 4];
            acc[k] = fmaf(v.x, c.x, acc[k]);
            acc[k] = fmaf(v.y, c.y, acc[k]);
            acc[k] = fmaf(v.z, c.z, acc[k]);
            acc[k] = fmaf(v.w, c.w, acc[k]);
        }
    }

    const int lab = labels[i];
    float sum_d = 0.f, sum_d2 = 0.f, d2_own = 0.f;
    #pragma unroll
    for (int k = 0; k < K; ++k) {
        float d2 = fmaf(-2.f, acc[k], x2 + sc2[k]);
        d2 = fmaxf(d2, 0.f);
        const float dd = __builtin_amdgcn_sqrtf(d2);
        sum_d += dd;
        sum_d2 += d2;
        if (k == lab) d2_own = d2;
    }
    const float d_own = __builtin_amdgcn_sqrtf(d2_own);
    const float rep_own = (MARGIN - d_own) * (MARGIN - d_own);
    const float rep_total = 25.f * K - 10.f * sum_d + sum_d2;
    const float row_other = (rep_total - rep_own) * (1.f / (K - 1));

    atomicAdd(&s_attr[lab], d2_own);
    atomicAdd(&s_rep[lab], row_other);
    atomicAdd(&s_cnt[lab], 1);
    __syncthreads();

    if (tid < K) {
        atomicAdd(&g_attr[tid], s_attr[tid]);
        atomicAdd(&g_rep[tid], s_rep[tid]);
        atomicAdd(&g_cnt[tid], s_cnt[tid]);
    }
}

__global__ void dcl_finish(const float* __restrict__ g_attr,
                           const float* __restrict__ g_rep,
                           const int*   __restrict__ g_cnt,
                           float* __restrict__ out)
{
    const int k = threadIdx.x;  // 64 threads = 1 wave
    const float cnt = (float)g_cnt[k];
    float v = (cnt > 0.f) ? (g_attr[k] + g_rep[k]) / cnt : 0.f;
    #pragma unroll
    for (int off = 32; off > 0; off >>= 1) v += __shfl_down(v, off);
    if (k == 0) out[0] = v * (1.f / K);
}

extern "C" void kernel_launch(void* const* d_in, const int* in_sizes, int n_in,
                              void* d_out, int out_size, void* d_ws, size_t ws_size,
                              hipStream_t stream) {
    const float* emb    = (const float*)d_in[0];
    const int*   labels = (const int*)d_in[1];
    const float* cent   = (const float*)d_in[2];
    float* out = (float*)d_out;

    float* g_attr = (float*)d_ws;
    float* g_rep  = g_attr + K;
    int*   g_cnt  = (int*)(g_rep + K);

    hipMemsetAsync(d_ws, 0, 3 * K * sizeof(float), stream);
    dcl_main<<<N / 256, 256, 0, stream>>>(emb, labels, cent, g_attr, g_rep, g_cnt);
    dcl_finish<<<1, 64, 0, stream>>>(g_attr, g_rep, g_cnt, out);
}

// Round 2
// 218.337 us; speedup vs baseline: 1.2011x; 1.2011x over previous
//
#include <hip/hip_runtime.h>

// DistanceCentroidLoss via bf16 MFMA: A=centroids (64 rows), B=points (32 cols/wave).
// d2 = x2 + c2 - 2*dot; rep row = (25K - 10*S1 + S2 - (5-d_own)^2)/(K-1); relu is no-op.
// C/D layout (32x32x16): col = lane&31 (point), row = (reg&3) + 8*(reg>>2) + 4*(lane>>5).
// A frag: lane holds A[m=lane&31][k=8*(lane>>5)+j]; B frag: B[k=8*(lane>>5)+j][n=lane&31].

constexpr int N = 262144;
constexpr int D = 128;
constexpr int K = 64;

constexpr int GRID = 1024;
constexpr int NWAVES = 4;                                    // 256 threads/block
constexpr int TILES_PER_WAVE = (N / 32) / (GRID * NWAVES);   // 8192 / 4096 = 2

typedef __bf16 bf16x8 __attribute__((ext_vector_type(8)));
typedef float  f32x16 __attribute__((ext_vector_type(16)));

__global__ __launch_bounds__(256) void dcl_main(
    const float* __restrict__ emb,
    const int*   __restrict__ labels,
    const float* __restrict__ cent,
    float* __restrict__ g_attr,
    float* __restrict__ g_rep,
    int*   __restrict__ g_cnt)
{
    __shared__ bf16x8 sA[2 * 8 * 64];   // 16 KB: [tile][kstep][lane] pre-swizzled A frags
    __shared__ float  s_c2[K];
    __shared__ float  s_attr[K];
    __shared__ float  s_rep[K];
    __shared__ int    s_cnt[K];

    const int tid = threadIdx.x;

    // --- stage centroid A-fragments into LDS (fragment order: 16B contiguous per lane) ---
    #pragma unroll
    for (int e = tid; e < 2 * 8 * 64; e += 256) {
        const int t = e >> 9, s = (e >> 6) & 7, l = e & 63;
        const int c  = t * 32 + (l & 31);
        const int d0 = 16 * s + 8 * (l >> 5);
        const float4 f0 = *(const float4*)(cent + c * D + d0);
        const float4 f1 = *(const float4*)(cent + c * D + d0 + 4);
        bf16x8 v;
        v[0] = (__bf16)f0.x; v[1] = (__bf16)f0.y; v[2] = (__bf16)f0.z; v[3] = (__bf16)f0.w;
        v[4] = (__bf16)f1.x; v[5] = (__bf16)f1.y; v[6] = (__bf16)f1.z; v[7] = (__bf16)f1.w;
        sA[e] = v;
    }
    if (tid < K) {
        const float4* cp = (const float4*)(cent + tid * D);
        float s = 0.f;
        #pragma unroll
        for (int q = 0; q < D / 4; ++q) {
            const float4 f = cp[q];
            s = fmaf(f.x, f.x, s); s = fmaf(f.y, f.y, s);
            s = fmaf(f.z, f.z, s); s = fmaf(f.w, f.w, s);
        }
        s_c2[tid] = s;
        s_attr[tid] = 0.f; s_rep[tid] = 0.f; s_cnt[tid] = 0;
    }
    __syncthreads();

    const int wave = tid >> 6;
    const int lane = tid & 63;
    const int l31  = lane & 31;
    const int h    = lane >> 5;

    for (int tt = 0; tt < TILES_PER_WAVE; ++tt) {
        const int tile = (blockIdx.x * NWAVES + wave) * TILES_PER_WAVE + tt;
        const int p    = tile * 32 + l31;
        const int lbl  = labels[p];
        const float* xrow = emb + (size_t)p * D + 8 * h;

        f32x16 acc0 = {0.f,0.f,0.f,0.f,0.f,0.f,0.f,0.f,0.f,0.f,0.f,0.f,0.f,0.f,0.f,0.f};
        f32x16 acc1 = {0.f,0.f,0.f,0.f,0.f,0.f,0.f,0.f,0.f,0.f,0.f,0.f,0.f,0.f,0.f,0.f};
        float x2p = 0.f;

        #pragma unroll
        for (int s = 0; s < 8; ++s) {
            const float4 f0 = *(const float4*)(xrow + 16 * s);
            const float4 f1 = *(const float4*)(xrow + 16 * s + 4);
            x2p = fmaf(f0.x, f0.x, x2p); x2p = fmaf(f0.y, f0.y, x2p);
            x2p = fmaf(f0.z, f0.z, x2p); x2p = fmaf(f0.w, f0.w, x2p);
            x2p = fmaf(f1.x, f1.x, x2p); x2p = fmaf(f1.y, f1.y, x2p);
            x2p = fmaf(f1.z, f1.z, x2p); x2p = fmaf(f1.w, f1.w, x2p);
            bf16x8 b;
            b[0] = (__bf16)f0.x; b[1] = (__bf16)f0.y; b[2] = (__bf16)f0.z; b[3] = (__bf16)f0.w;
            b[4] = (__bf16)f1.x; b[5] = (__bf16)f1.y; b[6] = (__bf16)f1.z; b[7] = (__bf16)f1.w;
            const bf16x8 a0 = sA[s * 64 + lane];
            const bf16x8 a1 = sA[(8 + s) * 64 + lane];
            acc0 = __builtin_amdgcn_mfma_f32_32x32x16_bf16(a0, b, acc0, 0, 0, 0);
            acc1 = __builtin_amdgcn_mfma_f32_32x32x16_bf16(a1, b, acc1, 0, 0, 0);
        }

        const float x2 = x2p + __shfl_xor(x2p, 32);

        float s1 = 0.f, s2 = 0.f, own = 0.f;
        #pragma unroll
        for (int r = 0; r < 16; ++r) {
            const int rbase = (r & 3) + 8 * (r >> 2) + 4 * h;
            {
                const float c2r = s_c2[rbase];
                float d2 = fmaf(-2.f, acc0[r], x2 + c2r);
                d2 = fmaxf(d2, 0.f);
                const float dd = __builtin_amdgcn_sqrtf(d2);
                s1 += dd; s2 += d2;
                if (rbase == lbl) own += d2;
            }
            {
                const int row = rbase + 32;
                const float c2r = s_c2[row];
                float d2 = fmaf(-2.f, acc1[r], x2 + c2r);
                d2 = fmaxf(d2, 0.f);
                const float dd = __builtin_amdgcn_sqrtf(d2);
                s1 += dd; s2 += d2;
                if (row == lbl) own += d2;
            }
        }
        s1  += __shfl_xor(s1, 32);
        s2  += __shfl_xor(s2, 32);
        own += __shfl_xor(own, 32);

        if (lane < 32) {
            const float down = __builtin_amdgcn_sqrtf(own);
            const float own_term = fmaf(-10.f, down, 25.f) + own;   // (5 - d_own)^2
            const float row_other = (25.f * K - 10.f * s1 + s2 - own_term) * (1.f / (K - 1));
            atomicAdd(&s_attr[lbl], own);
            atomicAdd(&s_rep[lbl], row_other);
            atomicAdd(&s_cnt[lbl], 1);
        }
    }

    __syncthreads();
    if (tid < K) {
        atomicAdd(&g_attr[tid], s_attr[tid]);
        atomicAdd(&g_rep[tid], s_rep[tid]);
        atomicAdd(&g_cnt[tid], s_cnt[tid]);
    }
}

__global__ void dcl_finish(const float* __restrict__ g_attr,
                           const float* __restrict__ g_rep,
                           const int*   __restrict__ g_cnt,
                           float* __restrict__ out)
{
    const int k = threadIdx.x;  // 64 threads = 1 wave
    const float cnt = (float)g_cnt[k];
    float v = (cnt > 0.f) ? (g_attr[k] + g_rep[k]) / cnt : 0.f;
    #pragma unroll
    for (int off = 32; off > 0; off >>= 1) v += __shfl_down(v, off);
    if (k == 0) out[0] = v * (1.f / K);
}

extern "C" void kernel_launch(void* const* d_in, const int* in_sizes, int n_in,
                              void* d_out, int out_size, void* d_ws, size_t ws_size,
                              hipStream_t stream) {
    const float* emb    = (const float*)d_in[0];
    const int*   labels = (const int*)d_in[1];
    const float* cent   = (const float*)d_in[2];
    float* out = (float*)d_out;

    float* g_attr = (float*)d_ws;
    float* g_rep  = g_attr + K;
    int*   g_cnt  = (int*)(g_rep + K);

    hipMemsetAsync(d_ws, 0, 3 * K * sizeof(float), stream);
    dcl_main<<<GRID, 256, 0, stream>>>(emb, labels, cent, g_attr, g_rep, g_cnt);
    dcl_finish<<<1, 64, 0, stream>>>(g_attr, g_rep, g_cnt, out);
}

// Round 3
// 207.446 us; speedup vs baseline: 1.2642x; 1.0525x over previous
//
#include <hip/hip_runtime.h>

// DistanceCentroidLoss via bf16 MFMA, round 3: contiguous wave loads + wave-private
// LDS transpose into B-fragment order (no barriers in the main loop).
// A=centroids (64 rows, 2 accumulators), B=points (32 cols/wave).
// d2 = x2 + c2 - 2*dot; rep row = (25K - 10*S1 + S2 - (5-d_own)^2)/(K-1); relu no-op.
// C/D layout (32x32x16): col = lane&31 (point), row = (reg&3) + 8*(reg>>2) + 4*(lane>>5).
// Panel layout: point n's chunk c (bf16x4 = 4 dwords of the row) at 8B-slot 34*n + c.
//   write: lane l, load q: n=2q+(l>>5), c=l&31  -> 2x contiguous 32-lane runs, 4/bank.
//   read : lane lam, step s: slots 34*(lam&31) + 4s+2h (+1) -> 16B aligned, 8 dw/bank.

constexpr int N = 262144;
constexpr int D = 128;
constexpr int K = 64;

constexpr int GRID = 1024;
constexpr int NWAVES = 4;                                 // 256 threads/block
constexpr int TPW = (N / 32) / (GRID * NWAVES);           // 2 tiles of 32 points per wave
constexpr int PANEL = 34 * 32;                            // bf16x4 slots per wave panel

typedef __bf16 bf16x4 __attribute__((ext_vector_type(4)));
typedef __bf16 bf16x8 __attribute__((ext_vector_type(8)));
typedef float  f32x16 __attribute__((ext_vector_type(16)));

__global__ __launch_bounds__(256) void dcl_main(
    const float* __restrict__ emb,
    const int*   __restrict__ labels,
    const float* __restrict__ cent,
    float* __restrict__ g_attr,
    float* __restrict__ g_rep,
    int*   __restrict__ g_cnt)
{
    __shared__ bf16x8 sA[2 * 8 * 64];                       // 16 KB A-fragments
    __shared__ __align__(16) bf16x4 sPanel[NWAVES * PANEL]; // 34 KB transpose panels
    __shared__ float  s_c2[K];
    __shared__ float  s_attr[K];
    __shared__ float  s_rep[K];
    __shared__ int    s_cnt[K];

    const int tid  = threadIdx.x;
    const int wave = tid >> 6;
    const int lane = tid & 63;
    const int l31  = lane & 31;
    const int h    = lane >> 5;

    const int tile0 = (blockIdx.x * NWAVES + wave) * TPW;

    // issue first tile's loads early (contiguous: lane strides 16 B)
    float4 buf[16];
    {
        const float4* src = (const float4*)emb + (size_t)tile0 * 1024 + lane;
        #pragma unroll
        for (int q = 0; q < 16; ++q) buf[q] = src[q * 64];
    }

    // --- stage centroid A-fragments into LDS (fragment order, 16B/lane) ---
    #pragma unroll
    for (int e = tid; e < 2 * 8 * 64; e += 256) {
        const int t = e >> 9, s = (e >> 6) & 7, l = e & 63;
        const int c  = t * 32 + (l & 31);
        const int d0 = 16 * s + 8 * (l >> 5);
        const float4 f0 = *(const float4*)(cent + c * D + d0);
        const float4 f1 = *(const float4*)(cent + c * D + d0 + 4);
        bf16x8 v;
        v[0] = (__bf16)f0.x; v[1] = (__bf16)f0.y; v[2] = (__bf16)f0.z; v[3] = (__bf16)f0.w;
        v[4] = (__bf16)f1.x; v[5] = (__bf16)f1.y; v[6] = (__bf16)f1.z; v[7] = (__bf16)f1.w;
        sA[e] = v;
    }
    if (tid < K) {
        const float4* cp = (const float4*)(cent + tid * D);
        float s = 0.f;
        #pragma unroll
        for (int q = 0; q < D / 4; ++q) {
            const float4 f = cp[q];
            s = fmaf(f.x, f.x, s); s = fmaf(f.y, f.y, s);
            s = fmaf(f.z, f.z, s); s = fmaf(f.w, f.w, s);
        }
        s_c2[tid] = s;
        s_attr[tid] = 0.f; s_rep[tid] = 0.f; s_cnt[tid] = 0;
    }
    __syncthreads();   // sA/s_c2 visible to all waves (only barrier besides the final one)

    bf16x4* panel = sPanel + wave * PANEL;

    for (int tt = 0; tt < TPW; ++tt) {
        const int tile = tile0 + tt;
        const int lbl  = labels[tile * 32 + l31];

        // convert current tile to bf16 and transpose into the panel (wave-private)
        #pragma unroll
        for (int q = 0; q < 16; ++q) {
            bf16x4 v;
            v[0] = (__bf16)buf[q].x; v[1] = (__bf16)buf[q].y;
            v[2] = (__bf16)buf[q].z; v[3] = (__bf16)buf[q].w;
            const int n = 2 * q + h;        // point within tile
            panel[34 * n + l31] = v;        // chunk c = l31
        }

        // prefetch next tile's global loads before the MFMA phase
        if (tt + 1 < TPW) {
            const float4* src = (const float4*)emb + (size_t)(tile + 1) * 1024 + lane;
            #pragma unroll
            for (int q = 0; q < 16; ++q) buf[q] = src[q * 64];
        }

        f32x16 acc0 = {0.f,0.f,0.f,0.f,0.f,0.f,0.f,0.f,0.f,0.f,0.f,0.f,0.f,0.f,0.f,0.f};
        f32x16 acc1 = {0.f,0.f,0.f,0.f,0.f,0.f,0.f,0.f,0.f,0.f,0.f,0.f,0.f,0.f,0.f,0.f};
        float x2p = 0.f;

        #pragma unroll
        for (int s = 0; s < 8; ++s) {
            // lane's own point's dwords [16s+8h, 16s+8h+8) as bf16
            const bf16x8 b = *(const bf16x8*)&panel[34 * l31 + 4 * s + 2 * h];
            #pragma unroll
            for (int e = 0; e < 8; ++e) {
                const float fe = (float)b[e];
                x2p = fmaf(fe, fe, x2p);
            }
            const bf16x8 a0 = sA[s * 64 + lane];
            const bf16x8 a1 = sA[(8 + s) * 64 + lane];
            acc0 = __builtin_amdgcn_mfma_f32_32x32x16_bf16(a0, b, acc0, 0, 0, 0);
            acc1 = __builtin_amdgcn_mfma_f32_32x32x16_bf16(a1, b, acc1, 0, 0, 0);
        }

        const float x2 = x2p + __shfl_xor(x2p, 32);

        float s1 = 0.f, s2 = 0.f, own = 0.f;
        #pragma unroll
        for (int r = 0; r < 16; ++r) {
            const int rbase = (r & 3) + 8 * (r >> 2) + 4 * h;
            {
                const float c2r = s_c2[rbase];
                float d2 = fmaf(-2.f, acc0[r], x2 + c2r);
                d2 = fmaxf(d2, 0.f);
                const float dd = __builtin_amdgcn_sqrtf(d2);
                s1 += dd; s2 += d2;
                if (rbase == lbl) own += d2;
            }
            {
                const int row = rbase + 32;
                const float c2r = s_c2[row];
                float d2 = fmaf(-2.f, acc1[r], x2 + c2r);
                d2 = fmaxf(d2, 0.f);
                const float dd = __builtin_amdgcn_sqrtf(d2);
                s1 += dd; s2 += d2;
                if (row == lbl) own += d2;
            }
        }
        s1  += __shfl_xor(s1, 32);
        s2  += __shfl_xor(s2, 32);
        own += __shfl_xor(own, 32);

        if (lane < 32) {
            const float down = __builtin_amdgcn_sqrtf(own);
            const float own_term = fmaf(-10.f, down, 25.f) + own;   // (5 - d_own)^2
            const float row_other = (25.f * K - 10.f * s1 + s2 - own_term) * (1.f / (K - 1));
            atomicAdd(&s_attr[lbl], own);
            atomicAdd(&s_rep[lbl], row_other);
            atomicAdd(&s_cnt[lbl], 1);
        }
    }

    __syncthreads();
    if (tid < K) {
        atomicAdd(&g_attr[tid], s_attr[tid]);
        atomicAdd(&g_rep[tid], s_rep[tid]);
        atomicAdd(&g_cnt[tid], s_cnt[tid]);
    }
}

__global__ void dcl_finish(const float* __restrict__ g_attr,
                           const float* __restrict__ g_rep,
                           const int*   __restrict__ g_cnt,
                           float* __restrict__ out)
{
    const int k = threadIdx.x;  // 64 threads = 1 wave
    const float cnt = (float)g_cnt[k];
    float v = (cnt > 0.f) ? (g_attr[k] + g_rep[k]) / cnt : 0.f;
    #pragma unroll
    for (int off = 32; off > 0; off >>= 1) v += __shfl_down(v, off);
    if (k == 0) out[0] = v * (1.f / K);
}

extern "C" void kernel_launch(void* const* d_in, const int* in_sizes, int n_in,
                              void* d_out, int out_size, void* d_ws, size_t ws_size,
                              hipStream_t stream) {
    const float* emb    = (const float*)d_in[0];
    const int*   labels = (const int*)d_in[1];
    const float* cent   = (const float*)d_in[2];
    float* out = (float*)d_out;

    float* g_attr = (float*)d_ws;
    float* g_rep  = g_attr + K;
    int*   g_cnt  = (int*)(g_rep + K);

    hipMemsetAsync(d_ws, 0, 3 * K * sizeof(float), stream);
    dcl_main<<<GRID, 256, 0, stream>>>(emb, labels, cent, g_attr, g_rep, g_cnt);
    dcl_finish<<<1, 64, 0, stream>>>(g_attr, g_rep, g_cnt, out);
}

// Round 4
// 204.980 us; speedup vs baseline: 1.2794x; 1.0120x over previous
//
#include <hip/hip_runtime.h>

// DistanceCentroidLoss via bf16 MFMA, round 4: GRID=512/TPW=4 (no grid tail,
// 3/4 tiles prefetched), c2 preloaded to registers for the epilogue.
// A=centroids (64 rows, 2 accumulators), B=points (32 cols/wave).
// d2 = x2 + c2 - 2*dot; rep row = (25K - 10*S1 + S2 - (5-d_own)^2)/(K-1); relu no-op.
// C/D layout (32x32x16): col = lane&31 (point), row = (reg&3) + 8*(reg>>2) + 4*(lane>>5).
// Panel layout: point n's chunk c (bf16x4) at 8B-slot 34*n + c (write 2-way, read 4-way max).

constexpr int N = 262144;
constexpr int D = 128;
constexpr int K = 64;

constexpr int GRID = 512;
constexpr int NWAVES = 4;                                 // 256 threads/block
constexpr int TPW = (N / 32) / (GRID * NWAVES);           // 4 tiles of 32 points per wave
constexpr int PANEL = 34 * 32;                            // bf16x4 slots per wave panel

typedef __bf16 bf16x4 __attribute__((ext_vector_type(4)));
typedef __bf16 bf16x8 __attribute__((ext_vector_type(8)));
typedef float  f32x16 __attribute__((ext_vector_type(16)));

__global__ __launch_bounds__(256) void dcl_main(
    const float* __restrict__ emb,
    const int*   __restrict__ labels,
    const float* __restrict__ cent,
    float* __restrict__ g_attr,
    float* __restrict__ g_rep,
    int*   __restrict__ g_cnt)
{
    __shared__ bf16x8 sA[2 * 8 * 64];                       // 16 KB A-fragments
    __shared__ __align__(16) bf16x4 sPanel[NWAVES * PANEL]; // 34 KB transpose panels
    __shared__ float  s_c2[K];
    __shared__ float  s_attr[K];
    __shared__ float  s_rep[K];
    __shared__ int    s_cnt[K];

    const int tid  = threadIdx.x;
    const int wave = tid >> 6;
    const int lane = tid & 63;
    const int l31  = lane & 31;
    const int h    = lane >> 5;

    const int tile0 = (blockIdx.x * NWAVES + wave) * TPW;

    // issue first tile's loads early (contiguous: lane strides 16 B, 1 KB/inst/wave)
    float4 buf[16];
    {
        const float4* src = (const float4*)emb + (size_t)tile0 * 1024 + lane;
        #pragma unroll
        for (int q = 0; q < 16; ++q) buf[q] = src[q * 64];
    }

    // --- stage centroid A-fragments into LDS (fragment order, 16B/lane) ---
    #pragma unroll
    for (int e = tid; e < 2 * 8 * 64; e += 256) {
        const int t = e >> 9, s = (e >> 6) & 7, l = e & 63;
        const int c  = t * 32 + (l & 31);
        const int d0 = 16 * s + 8 * (l >> 5);
        const float4 f0 = *(const float4*)(cent + c * D + d0);
        const float4 f1 = *(const float4*)(cent + c * D + d0 + 4);
        bf16x8 v;
        v[0] = (__bf16)f0.x; v[1] = (__bf16)f0.y; v[2] = (__bf16)f0.z; v[3] = (__bf16)f0.w;
        v[4] = (__bf16)f1.x; v[5] = (__bf16)f1.y; v[6] = (__bf16)f1.z; v[7] = (__bf16)f1.w;
        sA[e] = v;
    }
    if (tid < K) {
        const float4* cp = (const float4*)(cent + tid * D);
        float s = 0.f;
        #pragma unroll
        for (int q = 0; q < D / 4; ++q) {
            const float4 f = cp[q];
            s = fmaf(f.x, f.x, s); s = fmaf(f.y, f.y, s);
            s = fmaf(f.z, f.z, s); s = fmaf(f.w, f.w, s);
        }
        s_c2[tid] = s;
        s_attr[tid] = 0.f; s_rep[tid] = 0.f; s_cnt[tid] = 0;
    }
    __syncthreads();   // sA/s_c2 visible to all waves

    // preload the 32 per-lane c2 values used by the epilogue (reused by all tiles)
    float c2a[16], c2b[16];
    #pragma unroll
    for (int r = 0; r < 16; ++r) {
        const int rbase = (r & 3) + 8 * (r >> 2) + 4 * h;
        c2a[r] = s_c2[rbase];
        c2b[r] = s_c2[rbase + 32];
    }

    bf16x4* panel = sPanel + wave * PANEL;

    for (int tt = 0; tt < TPW; ++tt) {
        const int tile = tile0 + tt;
        const int lbl  = labels[tile * 32 + l31];

        // convert current tile to bf16 and transpose into the panel (wave-private)
        #pragma unroll
        for (int q = 0; q < 16; ++q) {
            bf16x4 v;
            v[0] = (__bf16)buf[q].x; v[1] = (__bf16)buf[q].y;
            v[2] = (__bf16)buf[q].z; v[3] = (__bf16)buf[q].w;
            const int n = 2 * q + h;        // point within tile
            panel[34 * n + l31] = v;        // chunk c = l31
        }

        // prefetch next tile's global loads before the MFMA phase
        if (tt + 1 < TPW) {
            const float4* src = (const float4*)emb + (size_t)(tile + 1) * 1024 + lane;
            #pragma unroll
            for (int q = 0; q < 16; ++q) buf[q] = src[q * 64];
        }

        f32x16 acc0 = {0.f,0.f,0.f,0.f,0.f,0.f,0.f,0.f,0.f,0.f,0.f,0.f,0.f,0.f,0.f,0.f};
        f32x16 acc1 = {0.f,0.f,0.f,0.f,0.f,0.f,0.f,0.f,0.f,0.f,0.f,0.f,0.f,0.f,0.f,0.f};
        float x2p = 0.f;

        #pragma unroll
        for (int s = 0; s < 8; ++s) {
            // lane's own point's dwords [16s+8h, 16s+8h+8) as bf16
            const bf16x8 b = *(const bf16x8*)&panel[34 * l31 + 4 * s + 2 * h];
            #pragma unroll
            for (int e = 0; e < 8; ++e) {
                const float fe = (float)b[e];
                x2p = fmaf(fe, fe, x2p);
            }
            const bf16x8 a0 = sA[s * 64 + lane];
            const bf16x8 a1 = sA[(8 + s) * 64 + lane];
            acc0 = __builtin_amdgcn_mfma_f32_32x32x16_bf16(a0, b, acc0, 0, 0, 0);
            acc1 = __builtin_amdgcn_mfma_f32_32x32x16_bf16(a1, b, acc1, 0, 0, 0);
        }

        const float x2 = x2p + __shfl_xor(x2p, 32);

        float s1 = 0.f, s2 = 0.f, own = 0.f;
        #pragma unroll
        for (int r = 0; r < 16; ++r) {
            const int rbase = (r & 3) + 8 * (r >> 2) + 4 * h;
            {
                float d2 = fmaf(-2.f, acc0[r], x2 + c2a[r]);
                d2 = fmaxf(d2, 0.f);
                const float dd = __builtin_amdgcn_sqrtf(d2);
                s1 += dd; s2 += d2;
                if (rbase == lbl) own += d2;
            }
            {
                float d2 = fmaf(-2.f, acc1[r], x2 + c2b[r]);
                d2 = fmaxf(d2, 0.f);
                const float dd = __builtin_amdgcn_sqrtf(d2);
                s1 += dd; s2 += d2;
                if (rbase + 32 == lbl) own += d2;
            }
        }
        s1  += __shfl_xor(s1, 32);
        s2  += __shfl_xor(s2, 32);
        own += __shfl_xor(own, 32);

        if (lane < 32) {
            const float down = __builtin_amdgcn_sqrtf(own);
            const float own_term = fmaf(-10.f, down, 25.f) + own;   // (5 - d_own)^2
            const float row_other = (25.f * K - 10.f * s1 + s2 - own_term) * (1.f / (K - 1));
            atomicAdd(&s_attr[lbl], own);
            atomicAdd(&s_rep[lbl], row_other);
            atomicAdd(&s_cnt[lbl], 1);
        }
    }

    __syncthreads();
    if (tid < K) {
        atomicAdd(&g_attr[tid], s_attr[tid]);
        atomicAdd(&g_rep[tid], s_rep[tid]);
        atomicAdd(&g_cnt[tid], s_cnt[tid]);
    }
}

__global__ void dcl_finish(const float* __restrict__ g_attr,
                           const float* __restrict__ g_rep,
                           const int*   __restrict__ g_cnt,
                           float* __restrict__ out)
{
    const int k = threadIdx.x;  // 64 threads = 1 wave
    const float cnt = (float)g_cnt[k];
    float v = (cnt > 0.f) ? (g_attr[k] + g_rep[k]) / cnt : 0.f;
    #pragma unroll
    for (int off = 32; off > 0; off >>= 1) v += __shfl_down(v, off);
    if (k == 0) out[0] = v * (1.f / K);
}

extern "C" void kernel_launch(void* const* d_in, const int* in_sizes, int n_in,
                              void* d_out, int out_size, void* d_ws, size_t ws_size,
                              hipStream_t stream) {
    const float* emb    = (const float*)d_in[0];
    const int*   labels = (const int*)d_in[1];
    const float* cent   = (const float*)d_in[2];
    float* out = (float*)d_out;

    float* g_attr = (float*)d_ws;
    float* g_rep  = g_attr + K;
    int*   g_cnt  = (int*)(g_rep + K);

    hipMemsetAsync(d_ws, 0, 3 * K * sizeof(float), stream);
    dcl_main<<<GRID, 256, 0, stream>>>(emb, labels, cent, g_attr, g_rep, g_cnt);
    dcl_finish<<<1, 64, 0, stream>>>(g_attr, g_rep, g_cnt, out);
}